// Round 1
// baseline (104.353 us; speedup 1.0000x reference)
//
#include <hip/hip_runtime.h>

// Problem constants (from reference): B=4, N=384, D=64, K=2
#define BB 4
#define NN 384
#define DD 64

#define R1 8   // rows per block, kernel 1
#define R2 8   // rows per block, kernel 2
#define CH 64  // l-chunk (contraction tile)

// Kernel 1: Y2[b,j,d] = sum_l A[b,j,l,1] * X[b,l,d,2]
// A layout: (B,N,N,2)  -> A[((b*N+j)*N+l)*2 + k]
// X layout: (B,N,D,3)  -> X[((b*N+l)*D+d)*3 + t]
// Y2 layout (ws): (B,N,D) contiguous
__global__ __launch_bounds__(256) void k1_y2(const float* __restrict__ A,
                                             const float* __restrict__ X,
                                             float* __restrict__ Y2) {
    __shared__ float Xs[CH][DD];   // X2 chunk: [l][d]
    __shared__ float As[R1][CH];   // A1 tile:  [row][l]

    const int b   = blockIdx.x / (NN / R1);
    const int j0  = (blockIdx.x % (NN / R1)) * R1;
    const int tid = threadIdx.x;
    const int lane = tid & 63;
    const int w    = tid >> 6;          // wave id 0..3
    const int r0   = w * 2;             // each wave owns 2 rows

    const float* Ab = A + (size_t)b * NN * NN * 2;
    const float* Xb = X + (size_t)b * NN * DD * 3;

    float acc0 = 0.f, acc1 = 0.f;

    for (int l0 = 0; l0 < NN; l0 += CH) {
        // stage X2 chunk: 64*64 = 4096 elems, 16 per thread
        #pragma unroll
        for (int it = 0; it < (CH * DD) / 256; ++it) {
            int idx = it * 256 + tid;
            int l = idx >> 6, d = idx & 63;
            Xs[l][d] = Xb[((l0 + l) * DD + d) * 3 + 2];
        }
        // stage A1 tile: 8*64 = 512 elems, 2 per thread
        #pragma unroll
        for (int it = 0; it < (R1 * CH) / 256; ++it) {
            int idx = it * 256 + tid;
            int r = idx >> 6, l = idx & 63;
            As[r][l] = Ab[((j0 + r) * NN + (l0 + l)) * 2 + 1];
        }
        __syncthreads();

        #pragma unroll
        for (int l = 0; l < CH; ++l) {
            float x = Xs[l][lane];            // stride-1 across lanes
            acc0 = fmaf(As[r0][l],     x, acc0);  // broadcast
            acc1 = fmaf(As[r0 + 1][l], x, acc1);
        }
        __syncthreads();
    }

    Y2[((size_t)b * NN + j0 + r0)     * DD + lane] = acc0;
    Y2[((size_t)b * NN + j0 + r0 + 1) * DD + lane] = acc1;
}

// Kernel 2: out[b,i,:] = (X0[b,i,:] + sum_j A0[b,i,j]*(X1[b,j,:]+Y2[b,j,:])) @ W
__global__ __launch_bounds__(256) void k2_out(const float* __restrict__ A,
                                              const float* __restrict__ X,
                                              const float* __restrict__ W,
                                              const float* __restrict__ Y2,
                                              float* __restrict__ out) {
    __shared__ float Vs[CH][DD];   // (X1 + Y2) chunk: [l][d]
    __shared__ float As[R2][CH];   // A0 tile: [row][l]
    __shared__ float Ws[DD][DD];   // readout matrix
    __shared__ float Ts[R2][DD];   // pre-readout rows

    const int b   = blockIdx.x / (NN / R2);
    const int i0  = (blockIdx.x % (NN / R2)) * R2;
    const int tid = threadIdx.x;
    const int lane = tid & 63;
    const int w    = tid >> 6;
    const int r0   = w * 2;

    // stage W once (coalesced), visible after first loop barrier
    #pragma unroll
    for (int it = 0; it < (DD * DD) / 256; ++it) {
        int idx = it * 256 + tid;
        Ws[idx >> 6][idx & 63] = W[idx];
    }

    const float* Ab = A  + (size_t)b * NN * NN * 2;
    const float* Xb = X  + (size_t)b * NN * DD * 3;
    const float* Yb = Y2 + (size_t)b * NN * DD;

    float acc0 = 0.f, acc1 = 0.f;

    for (int l0 = 0; l0 < NN; l0 += CH) {
        #pragma unroll
        for (int it = 0; it < (CH * DD) / 256; ++it) {
            int idx = it * 256 + tid;
            int l = idx >> 6, d = idx & 63;
            Vs[l][d] = Yb[(l0 + l) * DD + d]               // coalesced
                     + Xb[((l0 + l) * DD + d) * 3 + 1];    // stride-3
        }
        #pragma unroll
        for (int it = 0; it < (R2 * CH) / 256; ++it) {
            int idx = it * 256 + tid;
            int r = idx >> 6, l = idx & 63;
            As[r][l] = Ab[((i0 + r) * NN + (l0 + l)) * 2]; // k = 0
        }
        __syncthreads();

        #pragma unroll
        for (int l = 0; l < CH; ++l) {
            float v = Vs[l][lane];
            acc0 = fmaf(As[r0][l],     v, acc0);
            acc1 = fmaf(As[r0 + 1][l], v, acc1);
        }
        __syncthreads();
    }

    // T = X0 + A0@(X1+Y2)
    Ts[r0][lane]     = acc0 + Xb[((i0 + r0)     * DD + lane) * 3 + 0];
    Ts[r0 + 1][lane] = acc1 + Xb[((i0 + r0 + 1) * DD + lane) * 3 + 0];
    __syncthreads();

    // out[i,e] = sum_d T[i][d] * W[d][e], lane = e
    float o0 = 0.f, o1 = 0.f;
    #pragma unroll
    for (int d = 0; d < DD; ++d) {
        float we = Ws[d][lane];               // stride-1, conflict-free
        o0 = fmaf(Ts[r0][d],     we, o0);     // broadcast
        o1 = fmaf(Ts[r0 + 1][d], we, o1);
    }
    out[((size_t)b * NN + i0 + r0)     * DD + lane] = o0;
    out[((size_t)b * NN + i0 + r0 + 1) * DD + lane] = o1;
}

extern "C" void kernel_launch(void* const* d_in, const int* in_sizes, int n_in,
                              void* d_out, int out_size, void* d_ws, size_t ws_size,
                              hipStream_t stream) {
    const float* A = (const float*)d_in[0];
    const float* X = (const float*)d_in[1];
    const float* W = (const float*)d_in[2];
    float* out = (float*)d_out;
    float* Y2  = (float*)d_ws;   // needs B*N*D*4 = 393216 bytes

    dim3 block(256);
    dim3 grid1(BB * (NN / R1));
    dim3 grid2(BB * (NN / R2));
    hipLaunchKernelGGL(k1_y2, grid1, block, 0, stream, A, X, Y2);
    hipLaunchKernelGGL(k2_out, grid2, block, 0, stream, A, X, W, Y2, out);
}

// Round 4
// 99.378 us; speedup vs baseline: 1.0501x; 1.0501x over previous
//
#include <hip/hip_runtime.h>

// Problem constants: B=4, N=384, D=64, K=2 hops
#define BB 4
#define NN 384
#define DD 64

#define RPB   4                 // rows per block
#define SPLIT 4                 // K-slices per row (waves per row)
#define KS    (NN / SPLIT)      // 96 contraction steps per wave

// Kernel 1: U[b,j,d] = X[b,j,d,1] + sum_l A[b,j,l,1] * X[b,l,d,2]
// A: (B,N,N,2)  X: (B,N,D,3)  U (ws): (B,N,D) contiguous
__global__ __launch_bounds__(1024) void k1_u(const float* __restrict__ A,
                                             const float* __restrict__ X,
                                             float* __restrict__ U) {
    __shared__ float part[RPB * SPLIT][DD];

    const int tid  = threadIdx.x;
    const int lane = tid & 63;
    const int w    = tid >> 6;          // 0..15
    const int r    = w >> 2;            // row within block 0..3
    const int ks   = w & 3;             // K-slice 0..3

    const int b  = blockIdx.x / (NN / RPB);
    const int j0 = (blockIdx.x % (NN / RPB)) * RPB;
    const int j  = j0 + r;

    const float* Arow = A + (((size_t)b * NN + j) * NN) * 2 + 1;    // [l*2]
    const float* Xb   = X + (size_t)b * NN * DD * 3 + lane * 3 + 2; // [l*DD*3]

    float acc = 0.f;
    const int l0 = ks * KS;
    #pragma unroll 8
    for (int l = l0; l < l0 + KS; ++l)
        acc = fmaf(Arow[(size_t)l * 2], Xb[(size_t)l * DD * 3], acc);

    part[w][lane] = acc;
    __syncthreads();

    if (w < RPB) {
        const int jj = j0 + w;
        float u = X[(((size_t)b * NN + jj) * DD + lane) * 3 + 1];
        #pragma unroll
        for (int s = 0; s < SPLIT; ++s) u += part[w * SPLIT + s][lane];
        U[((size_t)b * NN + jj) * DD + lane] = u;
    }
}

// Kernel 2: out[b,i,:] = (X[b,i,:,0] + sum_l A[b,i,l,0] * U[b,l,:]) @ W
__global__ __launch_bounds__(1024) void k2_o(const float* __restrict__ A,
                                             const float* __restrict__ X,
                                             const float* __restrict__ W,
                                             const float* __restrict__ U,
                                             float* __restrict__ out) {
    __shared__ float part[RPB * SPLIT][DD];
    __shared__ float Ts[RPB][DD];
    __shared__ float Ws[DD][DD];

    const int tid  = threadIdx.x;
    const int lane = tid & 63;
    const int w    = tid >> 6;
    const int r    = w >> 2;
    const int ks   = w & 3;

    const int b  = blockIdx.x / (NN / RPB);
    const int i0 = (blockIdx.x % (NN / RPB)) * RPB;
    const int i  = i0 + r;

    // stage W (coalesced, 4 elems/thread); covered by the first barrier
    #pragma unroll
    for (int it = 0; it < (DD * DD) / 1024; ++it) {
        int idx = it * 1024 + tid;
        Ws[idx >> 6][idx & 63] = W[idx];
    }

    const float* Arow = A + (((size_t)b * NN + i) * NN) * 2;        // k=0
    const float* Ub   = U + (size_t)b * NN * DD + lane;

    float acc = 0.f;
    const int l0 = ks * KS;
    #pragma unroll 8
    for (int l = l0; l < l0 + KS; ++l)
        acc = fmaf(Arow[(size_t)l * 2], Ub[(size_t)l * DD], acc);

    part[w][lane] = acc;
    __syncthreads();

    if (w < RPB) {
        const int ii = i0 + w;
        float t = X[(((size_t)b * NN + ii) * DD + lane) * 3 + 0];
        #pragma unroll
        for (int s = 0; s < SPLIT; ++s) t += part[w * SPLIT + s][lane];
        Ts[w][lane] = t;
    }
    __syncthreads();

    if (w < RPB) {
        const int ii = i0 + w;
        float o = 0.f;
        #pragma unroll
        for (int d = 0; d < DD; ++d)
            o = fmaf(Ts[w][d], Ws[d][lane], o);   // Ts broadcast, Ws stride-1
        out[((size_t)b * NN + ii) * DD + lane] = o;
    }
}

extern "C" void kernel_launch(void* const* d_in, const int* in_sizes, int n_in,
                              void* d_out, int out_size, void* d_ws, size_t ws_size,
                              hipStream_t stream) {
    const float* A = (const float*)d_in[0];
    const float* X = (const float*)d_in[1];
    const float* W = (const float*)d_in[2];
    float* out = (float*)d_out;
    float* U   = (float*)d_ws;   // B*N*D*4 = 393216 bytes

    const dim3 block(RPB * SPLIT * 64);      // 1024
    const dim3 grid(BB * (NN / RPB));        // 384
    k1_u<<<grid, block, 0, stream>>>(A, X, U);
    k2_o<<<grid, block, 0, stream>>>(A, X, W, U, out);
}

// Round 5
// 81.159 us; speedup vs baseline: 1.2858x; 1.2245x over previous
//
#include <hip/hip_runtime.h>

// Problem constants: B=4, N=384, D=64, K=2 hops
#define BB 4
#define NN 384
#define DD 64
#define ANN (BB*NN*NN)        // 589824 : A1c elements
#define XND (BB*NN*DD)        // 98304  : one X time-slice
#define T0_TOTAL (ANN + 3*XND)

// ws layout (floats): [0,ANN): A1c[b][l][j] ; then X0c, X1c, X2c each [b][n][d]

__global__ __launch_bounds__(256) void t0_pack(const float* __restrict__ A,
                                               const float* __restrict__ X,
                                               float* __restrict__ ws) {
    int idx = blockIdx.x * 256 + threadIdx.x;
    if (idx >= T0_TOTAL) return;
    if (idx < ANN) {
        ws[idx] = A[(size_t)idx * 2 + 1];          // hop-1 slice, packed
    } else {
        int r = idx - ANN;
        int t = r / XND;                            // 0,1,2 time slice
        int e = r - t * XND;
        ws[idx] = X[(size_t)e * 3 + t];             // de-interleave X
    }
}

// LDS float offsets
#define LCL   0       // cl(h,r,j)  = (h*4+r)*384 + j      [12288]  (phase-1 partials)
#define LTP   0       // Tp(h,r,d)  = (h*4+r)*64 + d       [2048]   (overlays cl)
#define LTS   2048    // Ts(r,d)    = 2048 + r*64 + d      [256]    (overlays cl)
#define LCLF  12288   // clf(r,j)   = 12288 + r*384 + j    [1536]
#define LA0   13824   // A0s(r,j)   = 13824 + r*384 + j    [1536]
#define LW    15360   // Ws(d,e)    = 15360 + d*64 + e     [4096]
#define LTOT  19456   // 76 KiB -> 2 blocks/CU

// out[b,i,:] = (X0[i] + sum_j A0[i,j] X1[j] + sum_j (A0[i,:]@A1)[j] X2[j]) @ W
__global__ __launch_bounds__(512, 4) void gnn_fused(const float* __restrict__ A,
                                                    const float* __restrict__ W,
                                                    const float* __restrict__ ws,
                                                    float* __restrict__ out) {
    __shared__ __align__(16) float SM[LTOT];
    const int tid  = threadIdx.x;
    const int lane = tid & 63;
    const int w    = tid >> 6;                      // 0..7

    // XCD-aware swizzle: grid=384, 384%8==0 -> bijective
    const int lbid = ((int)blockIdx.x % 8) * 48 + (int)blockIdx.x / 8;
    const int b    = lbid / (NN / 4);
    const int i0   = (lbid % (NN / 4)) * 4;

    // ---- stage W (4096) and A0 rows (4x384, hop 0) ----
    #pragma unroll
    for (int it = 0; it < 8; ++it)
        SM[LW + it * 512 + tid] = W[it * 512 + tid];
    #pragma unroll
    for (int it = 0; it < 3; ++it) {
        int idx = it * 512 + tid;                   // < 1536
        int r = idx / 384, j = idx - r * 384;
        SM[LA0 + idx] = A[(((size_t)b * NN + i0 + r) * NN + j) * 2];  // hop 0
    }
    __syncthreads();

    // ---- phase 1: c[r][j] = sum_{l in slice} A0[r][l] * A1c[l][j] ----
    const float* A1b = ws + (size_t)b * NN * NN;
    float4 c4[4]; float2 c2[4];
    #pragma unroll
    for (int r = 0; r < 4; ++r) {
        c4[r].x = c4[r].y = c4[r].z = c4[r].w = 0.f;
        c2[r].x = c2[r].y = 0.f;
    }
    const int lbeg = w * 48;
    for (int l0 = lbeg; l0 < lbeg + 48; l0 += 4) {
        float4 a[4];
        #pragma unroll
        for (int r = 0; r < 4; ++r)
            a[r] = *(const float4*)&SM[LA0 + r * 384 + l0];   // uniform b128 bcast
        #pragma unroll
        for (int u = 0; u < 4; ++u) {
            const float* row = A1b + (size_t)(l0 + u) * NN;
            float4 v4 = *(const float4*)(row + lane * 4);          // j = lane*4..+3
            float2 v2 = *(const float2*)(row + 256 + lane * 2);    // j = 256+lane*2..+1
            #pragma unroll
            for (int r = 0; r < 4; ++r) {
                float av = (&a[r].x)[u];
                c4[r].x = fmaf(av, v4.x, c4[r].x);
                c4[r].y = fmaf(av, v4.y, c4[r].y);
                c4[r].z = fmaf(av, v4.z, c4[r].z);
                c4[r].w = fmaf(av, v4.w, c4[r].w);
                c2[r].x = fmaf(av, v2.x, c2[r].x);
                c2[r].y = fmaf(av, v2.y, c2[r].y);
            }
        }
    }
    // write partials
    #pragma unroll
    for (int r = 0; r < 4; ++r) {
        *(float4*)&SM[LCL + (w * 4 + r) * 384 + lane * 4] = c4[r];
        *(float2*)&SM[LCL + (w * 4 + r) * 384 + 256 + lane * 2] = c2[r];
    }
    __syncthreads();

    // ---- combine 8 l-slices -> clf ----
    if (w < 4) {
        const int r = w;
        float4 s4; float2 s2;
        s4.x = s4.y = s4.z = s4.w = 0.f; s2.x = s2.y = 0.f;
        #pragma unroll
        for (int h = 0; h < 8; ++h) {
            float4 p4 = *(const float4*)&SM[LCL + (h * 4 + r) * 384 + lane * 4];
            float2 p2 = *(const float2*)&SM[LCL + (h * 4 + r) * 384 + 256 + lane * 2];
            s4.x += p4.x; s4.y += p4.y; s4.z += p4.z; s4.w += p4.w;
            s2.x += p2.x; s2.y += p2.y;
        }
        *(float4*)&SM[LCLF + r * 384 + lane * 4] = s4;
        *(float2*)&SM[LCLF + r * 384 + 256 + lane * 2] = s2;
    }
    __syncthreads();

    // ---- phase 3: o[r][d] = sum_j clf[r][j]*X2c[j][d] + A0[r][j]*X1c[j][d] ----
    const float* X0c = ws + ANN;
    const float* X1c = X0c + XND;
    const float* X2c = X1c + XND;
    const int jsub = lane >> 4, dg = lane & 15;
    const float* X1b = X1c + (size_t)b * NN * DD + dg * 4;
    const float* X2b = X2c + (size_t)b * NN * DD + dg * 4;

    float4 o[4];
    #pragma unroll
    for (int r = 0; r < 4; ++r) { o[r].x = o[r].y = o[r].z = o[r].w = 0.f; }

    for (int g = 0; g < 12; ++g) {
        const int j = w * 48 + g * 4 + jsub;
        float4 x2 = *(const float4*)(X2b + j * 64);
        float4 x1 = *(const float4*)(X1b + j * 64);
        #pragma unroll
        for (int r = 0; r < 4; ++r) {
            float cf = SM[LCLF + r * 384 + j];
            float af = SM[LA0 + r * 384 + j];
            o[r].x = fmaf(cf, x2.x, fmaf(af, x1.x, o[r].x));
            o[r].y = fmaf(cf, x2.y, fmaf(af, x1.y, o[r].y));
            o[r].z = fmaf(cf, x2.z, fmaf(af, x1.z, o[r].z));
            o[r].w = fmaf(cf, x2.w, fmaf(af, x1.w, o[r].w));
        }
    }
    // reduce over the 4 jsub groups (lane^16, lane^32)
    #pragma unroll
    for (int r = 0; r < 4; ++r) {
        o[r].x += __shfl_xor(o[r].x, 16); o[r].y += __shfl_xor(o[r].y, 16);
        o[r].z += __shfl_xor(o[r].z, 16); o[r].w += __shfl_xor(o[r].w, 16);
        o[r].x += __shfl_xor(o[r].x, 32); o[r].y += __shfl_xor(o[r].y, 32);
        o[r].z += __shfl_xor(o[r].z, 32); o[r].w += __shfl_xor(o[r].w, 32);
    }
    if (jsub == 0) {
        #pragma unroll
        for (int r = 0; r < 4; ++r)
            *(float4*)&SM[LTP + (w * 4 + r) * 64 + dg * 4] = o[r];
    }
    __syncthreads();

    // ---- combine 8 j-slices + X0, then readout @W ----
    if (w < 4) {
        float t = X0c[((size_t)b * NN + i0 + w) * DD + lane];
        #pragma unroll
        for (int h = 0; h < 8; ++h) t += SM[LTP + (h * 4 + w) * 64 + lane];
        SM[LTS + w * 64 + lane] = t;
    }
    __syncthreads();
    if (w < 4) {
        float acc = 0.f;
        #pragma unroll 8
        for (int d = 0; d < DD; ++d)
            acc = fmaf(SM[LTS + w * 64 + d], SM[LW + d * 64 + lane], acc);
        out[((size_t)b * NN + i0 + w) * DD + lane] = acc;
    }
}

extern "C" void kernel_launch(void* const* d_in, const int* in_sizes, int n_in,
                              void* d_out, int out_size, void* d_ws, size_t ws_size,
                              hipStream_t stream) {
    const float* A = (const float*)d_in[0];
    const float* X = (const float*)d_in[1];
    const float* W = (const float*)d_in[2];
    float* out = (float*)d_out;
    float* ws  = (float*)d_ws;   // uses (ANN + 3*XND)*4 = ~3.5 MB

    t0_pack<<<dim3((T0_TOTAL + 255) / 256), dim3(256), 0, stream>>>(A, X, ws);
    gnn_fused<<<dim3(BB * (NN / 4)), dim3(512), 0, stream>>>(A, W, ws, out);
}

// Round 8
// 72.593 us; speedup vs baseline: 1.4375x; 1.1180x over previous
//
#include <hip/hip_runtime.h>

// B=4, N=384, D=64, K=2 hops
#define BB 4
#define NN 384
#define DD 64
#define XND (BB*NN*DD)   // 98304 floats per X time-slice

// ws layout (floats): [0, XND) = X2c packed [b][l][d] ; [XND, 2*XND) = U [b][j][d]

__global__ __launch_bounds__(256) void g1_pack(const float* __restrict__ X,
                                               float* __restrict__ ws) {
    const int idx = blockIdx.x * 256 + threadIdx.x;   // grid covers XND exactly
    ws[idx] = X[(size_t)idx * 3 + 2];                 // de-interleave t=2 slice
}

#define FMA4(c, a, x)                          \
    c.x = fmaf(a, x.x, c.x);                   \
    c.y = fmaf(a, x.y, c.y);                   \
    c.z = fmaf(a, x.z, c.z);                   \
    c.w = fmaf(a, x.w, c.w);

#define RED4(c)                                                         \
    c.x += __shfl_xor(c.x, 16); c.y += __shfl_xor(c.y, 16);             \
    c.z += __shfl_xor(c.z, 16); c.w += __shfl_xor(c.w, 16);             \
    c.x += __shfl_xor(c.x, 32); c.y += __shfl_xor(c.y, 32);             \
    c.z += __shfl_xor(c.z, 32); c.w += __shfl_xor(c.w, 32);

// U[b,j,d] = X[b,j,d,1] + sum_l A[b,j,l,1] * X2c[b,l,d]
// block = 4 rows; wave ks = K-quarter (96 l's); lane = (jsub = l mod 4, dg = d quad)
__global__ __launch_bounds__(256) void g2_u(const float* __restrict__ A,
                                            const float* __restrict__ X,
                                            float* __restrict__ ws) {
    __shared__ float part[4][4][DD];
    const float* X2c = ws;
    float* U = ws + XND;

    const int tid = threadIdx.x, lane = tid & 63, ks = tid >> 6;
    const int dg = lane & 15, jsub = lane >> 4;
    const int lbid = ((int)blockIdx.x & 7) * 48 + ((int)blockIdx.x >> 3); // XCD swizzle, 384%8==0
    const int b = lbid / 96, j0 = (lbid % 96) * 4;

    const int lb = ks * 96 + jsub;
    const float* xp = X2c + ((size_t)b * NN + lb) * DD + dg * 4;
    const float* a0 = A + (((size_t)b * NN + j0 + 0) * NN + lb) * 2 + 1;
    const float* a1 = A + (((size_t)b * NN + j0 + 1) * NN + lb) * 2 + 1;
    const float* a2 = A + (((size_t)b * NN + j0 + 2) * NN + lb) * 2 + 1;
    const float* a3 = A + (((size_t)b * NN + j0 + 3) * NN + lb) * 2 + 1;

    float4 c0{0,0,0,0}, c1{0,0,0,0}, c2{0,0,0,0}, c3{0,0,0,0};
    #pragma unroll 8
    for (int s = 0; s < 24; ++s) {              // l = lb + s*4
        float4 x = *(const float4*)(xp + s * 4 * DD);
        float v0 = a0[s * 8], v1 = a1[s * 8], v2 = a2[s * 8], v3 = a3[s * 8];
        FMA4(c0, v0, x) FMA4(c1, v1, x) FMA4(c2, v2, x) FMA4(c3, v3, x)
    }
    RED4(c0) RED4(c1) RED4(c2) RED4(c3)
    if (jsub == 0) {
        *(float4*)&part[ks][0][dg * 4] = c0;
        *(float4*)&part[ks][1][dg * 4] = c1;
        *(float4*)&part[ks][2][dg * 4] = c2;
        *(float4*)&part[ks][3][dg * 4] = c3;
    }
    __syncthreads();

    const int w = ks;                            // wave w -> row j0+w
    float t = X[(((size_t)b * NN + j0 + w) * DD + lane) * 3 + 1];
    t += part[0][w][lane] + part[1][w][lane] + part[2][w][lane] + part[3][w][lane];
    U[((size_t)b * NN + j0 + w) * DD + lane] = t;
}

// out[b,i,:] = (X[b,i,:,0] + sum_j A[b,i,j,0] * U[b,j,:]) @ W
__global__ __launch_bounds__(256) void g3_out(const float* __restrict__ A,
                                              const float* __restrict__ X,
                                              const float* __restrict__ W,
                                              const float* __restrict__ ws,
                                              float* __restrict__ out) {
    __shared__ float part[4][4][DD];
    __shared__ float Ts[4][DD];
    __shared__ float Wsm[DD * DD];
    const float* U = ws + XND;

    const int tid = threadIdx.x, lane = tid & 63, ks = tid >> 6;
    const int dg = lane & 15, jsub = lane >> 4;
    const int lbid = ((int)blockIdx.x & 7) * 48 + ((int)blockIdx.x >> 3);
    const int b = lbid / 96, i0 = (lbid % 96) * 4;

    // stage W (coalesced float4), visible after first barrier
    #pragma unroll
    for (int it = 0; it < 4; ++it) {
        int i4 = it * 256 + tid;
        *(float4*)&Wsm[i4 * 4] = ((const float4*)W)[i4];
    }

    const int lb = ks * 96 + jsub;
    const float* xp = U + ((size_t)b * NN + lb) * DD + dg * 4;
    const float* a0 = A + (((size_t)b * NN + i0 + 0) * NN + lb) * 2;   // hop 0
    const float* a1 = A + (((size_t)b * NN + i0 + 1) * NN + lb) * 2;
    const float* a2 = A + (((size_t)b * NN + i0 + 2) * NN + lb) * 2;
    const float* a3 = A + (((size_t)b * NN + i0 + 3) * NN + lb) * 2;

    float4 c0{0,0,0,0}, c1{0,0,0,0}, c2{0,0,0,0}, c3{0,0,0,0};
    #pragma unroll 8
    for (int s = 0; s < 24; ++s) {
        float4 x = *(const float4*)(xp + s * 4 * DD);
        float v0 = a0[s * 8], v1 = a1[s * 8], v2 = a2[s * 8], v3 = a3[s * 8];
        FMA4(c0, v0, x) FMA4(c1, v1, x) FMA4(c2, v2, x) FMA4(c3, v3, x)
    }
    RED4(c0) RED4(c1) RED4(c2) RED4(c3)
    if (jsub == 0) {
        *(float4*)&part[ks][0][dg * 4] = c0;
        *(float4*)&part[ks][1][dg * 4] = c1;
        *(float4*)&part[ks][2][dg * 4] = c2;
        *(float4*)&part[ks][3][dg * 4] = c3;
    }
    __syncthreads();

    const int w = ks;
    float t = X[(((size_t)b * NN + i0 + w) * DD + lane) * 3 + 0];
    t += part[0][w][lane] + part[1][w][lane] + part[2][w][lane] + part[3][w][lane];
    Ts[w][lane] = t;
    __syncthreads();

    float o = 0.f;
    #pragma unroll 16
    for (int d = 0; d < DD; ++d)
        o = fmaf(Ts[w][d], Wsm[d * DD + lane], o);   // broadcast * stride-1
    out[((size_t)b * NN + i0 + w) * DD + lane] = o;
}

extern "C" void kernel_launch(void* const* d_in, const int* in_sizes, int n_in,
                              void* d_out, int out_size, void* d_ws, size_t ws_size,
                              hipStream_t stream) {
    const float* A = (const float*)d_in[0];
    const float* X = (const float*)d_in[1];
    const float* W = (const float*)d_in[2];
    float* out = (float*)d_out;
    float* ws  = (float*)d_ws;   // uses 2*XND*4 = 786432 bytes

    g1_pack<<<dim3(XND / 256), dim3(256), 0, stream>>>(X, ws);
    g2_u  <<<dim3(BB * NN / 4), dim3(256), 0, stream>>>(A, X, ws);
    g3_out<<<dim3(BB * NN / 4), dim3(256), 0, stream>>>(A, X, W, ws, out);
}